// Round 6
// baseline (216.570 us; speedup 1.0000x reference)
//
#include <hip/hip_runtime.h>
#include <math.h>

#define EMB 32

// v4: barrier-free wave-decoupled version.
//  - Each wave stages its OWN copy of the weights into a wave-private LDS
//    region (1184 floats/wave). Same-wave ds_write->ds_read ordering is
//    enforced by compiler lgkmcnt; NO __syncthreads in the kernel.
//    This removes the vmcnt(0)+barrier drain that previously forced every
//    wave to wait for ALL its gathers (and all 4 waves of the block to wait
//    for the slowest random gather) before any compute.
//  - VMEM issue order chosen so every wait is a counted vmcnt, never a
//    full drain: idx -> staging -> member-idx -> item(e0,e1) ->
//    member rows(e0,e1) -> compute e0 (e1 rows still in flight) -> e1.
//  - git fold: g*it (.)wa + g(.)wb == g(.)(it*wa+wb): saves 16 VGPRs.
// Block = 256 threads (4 waves), 64 groups x 2 elements = 128 elem/block.
// Grid = 1024. __launch_bounds__(256,4): <=128 VGPR -> 16 waves/CU.
__global__ __launch_bounds__(256, 4) void bahdanau_fused(
    const int* __restrict__ group_inputs,   // [B]
    const int* __restrict__ item_inputs,    // [B]
    const int* __restrict__ members,        // [500000][3]
    const float* __restrict__ user_emb,     // [1000000][32]
    const float* __restrict__ item_emb,     // [100000][14]
    const float* __restrict__ genres,       // [100000][18]
    const float* __restrict__ attn_W,       // [128][3]
    const float* __restrict__ attn_b,       // [3]
    const float* __restrict__ pred_W1,      // [96][8]
    const float* __restrict__ pred_b1,      // [8]
    const float* __restrict__ pred_W2,      // [8][1]
    const float* __restrict__ pred_b2,      // [1]
    float* __restrict__ out)                // [B]
{
    // Wave-private staging: [wave][1184] floats.
    // Layout within a wave's region:
    //   aWT  @ 0     [3][128]  (transposed attn_W, [k][d])
    //   W1T  @ 384   [8][96]   (transposed pred_W1, [c][r])
    //   ab   @ 1152  [3]
    //   b1   @ 1155  [8]
    //   W2   @ 1163  [8]
    //   b2   @ 1171  [1]
    __shared__ float smem[4 * 1184];

    const int tid  = threadIdx.x;
    const int lane = tid & 63;
    float* sw = smem + (tid >> 6) * 1184;

    const int t = tid & 3;                          // dim-slice owner
    const int grp = tid >> 2;                       // 0..63 (block-wide)
    const int ebase = blockIdx.x * 128 + grp * 2;   // group's 2 elements
    const int dbase = t * 8;

    // ---- 1. Element indices (oldest VMEM; int2 vector loads) ----
    const int2 gpair = *(const int2*)&group_inputs[ebase];
    const int2 ipair = *(const int2*)&item_inputs[ebase];

    // ---- 2. Per-wave weight staging (loads + ds_writes) ----
    // 1172 floats / 64 lanes = 19 strided iterations. Branch ranges are
    // 64-aligned (384 = 6*64, 1152 = 18*64) so all but the last iteration
    // are wave-uniform. These loads are L1/L2 hits (all waves hit the same
    // lines); their latency hides under the gather chain below.
#pragma unroll
    for (int it = 0; it < 19; ++it) {
        const int i = lane + it * 64;
        float v;
        if (i < 384) {
            const int k = i >> 7, d = i & 127;
            v = attn_W[d * 3 + k];
        } else if (i < 1152) {
            const int r2 = i - 384, c = r2 / 96, r = r2 - c * 96;
            v = pred_W1[r * 8 + c];
        } else if (i < 1155) v = attn_b[i - 1152];
        else if (i < 1163)   v = pred_b1[i - 1155];
        else if (i < 1171)   v = pred_W2[i - 1163];
        else                 v = pred_b2[0];       // i == 1171 (+ pad lanes)
        if (i < 1172) sw[i] = v;
        else if (i < 1184) sw[i] = 0.0f;           // pad
    }

    // ---- 3. Member indices (depend on gpair only) ----
    const int g0 = gpair.x, g1 = gpair.y;
    const int i0 = ipair.x, i1 = ipair.y;
    int m0[3], m1[3];
#pragma unroll
    for (int j = 0; j < 3; ++j) {
        m0[j] = members[3 * g0 + j];
        m1[j] = members[3 * g1 + j];
    }

    // ---- 4. Item vectors, e0 then e1 (depend on ipair only) ----
    float itv0[8], itv1[8];
#pragma unroll
    for (int i = 0; i < 4; ++i) {
        const int d = dbase + 2 * i;
        const float2* p0 = (d < 14)
            ? (const float2*)(item_emb + (size_t)i0 * 14 + d)
            : (const float2*)(genres   + (size_t)i0 * 18 + (d - 14));
        const float2 a = *p0;
        itv0[2 * i] = a.x; itv0[2 * i + 1] = a.y;
    }
#pragma unroll
    for (int i = 0; i < 4; ++i) {
        const int d = dbase + 2 * i;
        const float2* p1 = (d < 14)
            ? (const float2*)(item_emb + (size_t)i1 * 14 + d)
            : (const float2*)(genres   + (size_t)i1 * 18 + (d - 14));
        const float2 b = *p1;
        itv1[2 * i] = b.x; itv1[2 * i + 1] = b.y;
    }

    // ---- 5. Member row gathers: e0's 6 loads first, then e1's ----
    float mem0[3][8], mem1[3][8];
#pragma unroll
    for (int j = 0; j < 3; ++j) {
        const float4* p0 = (const float4*)(user_emb + (size_t)m0[j] * EMB + dbase);
        float4 a = p0[0], b = p0[1];
        mem0[j][0] = a.x; mem0[j][1] = a.y; mem0[j][2] = a.z; mem0[j][3] = a.w;
        mem0[j][4] = b.x; mem0[j][5] = b.y; mem0[j][6] = b.z; mem0[j][7] = b.w;
    }
#pragma unroll
    for (int j = 0; j < 3; ++j) {
        const float4* p1 = (const float4*)(user_emb + (size_t)m1[j] * EMB + dbase);
        float4 c = p1[0], d = p1[1];
        mem1[j][0] = c.x; mem1[j][1] = c.y; mem1[j][2] = c.z; mem1[j][3] = c.w;
        mem1[j][4] = d.x; mem1[j][5] = d.y; mem1[j][6] = d.z; mem1[j][7] = d.w;
    }

    // ---- 6. Compute element 0 (e1's member rows may still be in flight) ----
    float hq0, hq1;
    {
        float aw[3];
#pragma unroll
        for (int k = 0; k < 3; ++k) {
            float a0 = 0.f;
#pragma unroll
            for (int j = 0; j < 3; ++j) {
                const float4* wp = (const float4*)&sw[k * 128 + j * 32 + dbase];
                float4 wl = wp[0], wh = wp[1];
                float w[8] = {wl.x, wl.y, wl.z, wl.w, wh.x, wh.y, wh.z, wh.w};
#pragma unroll
                for (int i = 0; i < 8; ++i) a0 = fmaf(mem0[j][i], w[i], a0);
            }
            const float4* wp = (const float4*)&sw[k * 128 + 96 + dbase];
            float4 wl = wp[0], wh = wp[1];
            float w[8] = {wl.x, wl.y, wl.z, wl.w, wh.x, wh.y, wh.z, wh.w};
#pragma unroll
            for (int i = 0; i < 8; ++i) a0 = fmaf(itv0[i], w[i], a0);
            a0 += __shfl_xor(a0, 1, 4);
            a0 += __shfl_xor(a0, 2, 4);
            aw[k] = a0 + sw[1152 + k];
        }
        float gv[8];
#pragma unroll
        for (int i = 0; i < 8; ++i)
            gv[i] = aw[0] * mem0[0][i] + aw[1] * mem0[1][i] + aw[2] * mem0[2][i];
        float ph[8];
#pragma unroll
        for (int c = 0; c < 8; ++c) {
            const float4* wpa = (const float4*)&sw[384 + c * 96 + dbase];
            const float4* wpb = (const float4*)&sw[384 + c * 96 + 32 + dbase];
            const float4* wpc = (const float4*)&sw[384 + c * 96 + 64 + dbase];
            float4 al = wpa[0], ah = wpa[1];
            float4 bl = wpb[0], bh = wpb[1];
            float4 cl = wpc[0], ch = wpc[1];
            float wa[8] = {al.x, al.y, al.z, al.w, ah.x, ah.y, ah.z, ah.w};
            float wb[8] = {bl.x, bl.y, bl.z, bl.w, bh.x, bh.y, bh.z, bh.w};
            float wc[8] = {cl.x, cl.y, cl.z, cl.w, ch.x, ch.y, ch.z, ch.w};
            float a0 = 0.f;
#pragma unroll
            for (int i = 0; i < 8; ++i) {
                a0 = fmaf(gv[i], fmaf(itv0[i], wa[i], wb[i]), a0);  // g*it.wa + g.wb
                a0 = fmaf(itv0[i], wc[i], a0);
            }
            ph[c] = a0;
        }
        float y = sw[1171];
#pragma unroll
        for (int c = 0; c < 8; ++c) {
            float v = ph[c];
            v += __shfl_xor(v, 1, 4);
            v += __shfl_xor(v, 2, 4);
            float h = fmaxf(v + sw[1155 + c], 0.0f);
            y = fmaf(h, sw[1163 + c], y);
        }
        hq0 = y;
    }

    // ---- 7. Compute element 1 ----
    {
        float aw[3];
#pragma unroll
        for (int k = 0; k < 3; ++k) {
            float a1 = 0.f;
#pragma unroll
            for (int j = 0; j < 3; ++j) {
                const float4* wp = (const float4*)&sw[k * 128 + j * 32 + dbase];
                float4 wl = wp[0], wh = wp[1];
                float w[8] = {wl.x, wl.y, wl.z, wl.w, wh.x, wh.y, wh.z, wh.w};
#pragma unroll
                for (int i = 0; i < 8; ++i) a1 = fmaf(mem1[j][i], w[i], a1);
            }
            const float4* wp = (const float4*)&sw[k * 128 + 96 + dbase];
            float4 wl = wp[0], wh = wp[1];
            float w[8] = {wl.x, wl.y, wl.z, wl.w, wh.x, wh.y, wh.z, wh.w};
#pragma unroll
            for (int i = 0; i < 8; ++i) a1 = fmaf(itv1[i], w[i], a1);
            a1 += __shfl_xor(a1, 1, 4);
            a1 += __shfl_xor(a1, 2, 4);
            aw[k] = a1 + sw[1152 + k];
        }
        float gv[8];
#pragma unroll
        for (int i = 0; i < 8; ++i)
            gv[i] = aw[0] * mem1[0][i] + aw[1] * mem1[1][i] + aw[2] * mem1[2][i];
        float ph[8];
#pragma unroll
        for (int c = 0; c < 8; ++c) {
            const float4* wpa = (const float4*)&sw[384 + c * 96 + dbase];
            const float4* wpb = (const float4*)&sw[384 + c * 96 + 32 + dbase];
            const float4* wpc = (const float4*)&sw[384 + c * 96 + 64 + dbase];
            float4 al = wpa[0], ah = wpa[1];
            float4 bl = wpb[0], bh = wpb[1];
            float4 cl = wpc[0], ch = wpc[1];
            float wa[8] = {al.x, al.y, al.z, al.w, ah.x, ah.y, ah.z, ah.w};
            float wb[8] = {bl.x, bl.y, bl.z, bl.w, bh.x, bh.y, bh.z, bh.w};
            float wc[8] = {cl.x, cl.y, cl.z, cl.w, ch.x, ch.y, ch.z, ch.w};
            float a1 = 0.f;
#pragma unroll
            for (int i = 0; i < 8; ++i) {
                a1 = fmaf(gv[i], fmaf(itv1[i], wa[i], wb[i]), a1);
                a1 = fmaf(itv1[i], wc[i], a1);
            }
            ph[c] = a1;
        }
        float y = sw[1171];
#pragma unroll
        for (int c = 0; c < 8; ++c) {
            float v = ph[c];
            v += __shfl_xor(v, 1, 4);
            v += __shfl_xor(v, 2, 4);
            float h = fmaxf(v + sw[1155 + c], 0.0f);
            y = fmaf(h, sw[1163 + c], y);
        }
        hq1 = y;
    }

    // ---- 8. Sigmoid + store (lane t<2 stores element ebase+t) ----
    if (t < 2) {
        float y = (t == 0) ? hq0 : hq1;
        y = 1.0f / (1.0f + expf(-y));
        out[ebase + t] = y;
    }
}

extern "C" void kernel_launch(void* const* d_in, const int* in_sizes, int n_in,
                              void* d_out, int out_size, void* d_ws, size_t ws_size,
                              hipStream_t stream) {
    const int*   group_inputs = (const int*)d_in[0];
    const int*   item_inputs  = (const int*)d_in[1];
    const int*   members      = (const int*)d_in[2];
    const float* user_emb     = (const float*)d_in[3];
    const float* item_emb     = (const float*)d_in[4];
    const float* genres       = (const float*)d_in[5];
    const float* attn_W       = (const float*)d_in[6];
    const float* attn_b       = (const float*)d_in[7];
    const float* pred_W1      = (const float*)d_in[8];
    const float* pred_b1      = (const float*)d_in[9];
    const float* pred_W2      = (const float*)d_in[10];
    const float* pred_b2      = (const float*)d_in[11];
    float* out = (float*)d_out;

    const int B = in_sizes[0];           // 131072
    const int blocks = B / 128;          // 1024 blocks, 128 elements each

    bahdanau_fused<<<blocks, 256, 0, stream>>>(
        group_inputs, item_inputs, members, user_emb, item_emb, genres,
        attn_W, attn_b, pred_W1, pred_b1, pred_W2, pred_b2, out);
}